// Round 9
// baseline (185.064 us; speedup 1.0000x reference)
//
#include <hip/hip_runtime.h>
#include <hip/hip_fp16.h>

// GCN layer on MI355X — fused atomic-free CSR build (single kernel, grid
// barriers), fp16 MFMA GEMM, CSR gather.
// out[c] = dis[c] * ( sum_{e: dst=c} t2[src_e] + t2[c] ) + bias
// t2[i] = dis[i] * (x @ W)[i], dis[i] = rsqrt(1 + outdeg(i)).
//
// Round-8 post-mortem: single-block WhT transpose (fold into k_scan2) was a
// serial one-CU tail, and the split-wave gather was neutral-to-negative ->
// reverted to r7 gather. This round fuses the whole 5-kernel build chain into
// ONE kernel (196 blocks <= 256 CUs, co-resident; device-scope atomic grid
// barriers; counter zeroed via hipMemsetAsync per call so graph replays are
// deterministic). Fusion also lets each block keep its 4096-edge chunk in LDS
// across phases (hist -> part, saves a 6.4MB re-read) and runs the WhT
// transpose on 64 idle blocks in parallel with the scan.

#define EPB 4096  // edges per build block

typedef _Float16 f16;
typedef f16 f16x8 __attribute__((ext_vector_type(8)));
typedef float f32x4 __attribute__((ext_vector_type(4)));

static inline int cdiv(int a, int b) { return (a + b - 1) / b; }

// Monotone-counter grid barrier. All NG blocks co-resident (NG <= #CUs).
// cnt is zeroed by hipMemsetAsync before the kernel each call.
__device__ __forceinline__ void grid_bar(int* cnt, int target, int tid) {
  __syncthreads();
  if (tid == 0) {
    __threadfence();  // flush this block's writes to device scope
    __hip_atomic_fetch_add(cnt, 1, __ATOMIC_RELEASE, __HIP_MEMORY_SCOPE_AGENT);
    while (__hip_atomic_load(cnt, __ATOMIC_ACQUIRE, __HIP_MEMORY_SCOPE_AGENT) < target) {}
  }
  __syncthreads();
}

// Fused build: P1 hist -> P2 (scan1 || WhT) -> P3 scan2 -> P4 part -> P5 bucket.
// hist layout: hist[bin*nblk + blk] (dst) and hist[HALF + bin*nblk + blk] (src).
__global__ __launch_bounds__(256) void k_build(
    const int* __restrict__ ei, int E, int N,
    int nblk, int nbins, int nb1, int NG,
    int* __restrict__ hist, int* __restrict__ partials,
    int* __restrict__ ebA, unsigned char* __restrict__ ebB,
    float* __restrict__ dis, int* __restrict__ offs, int* __restrict__ srcs,
    const float* __restrict__ W, f16* __restrict__ WhT, int* cnt) {
  __shared__ int esrc[EPB], edst[EPB];   // this block's edge chunk (P1 -> P4)
  __shared__ int shA[256], shB[256], shC[256];
  const int tid = threadIdx.x, blk = blockIdx.x;
  const int HALF = nbins * nblk;

  // ---- P1: coarse histograms; stash edges in LDS ----
  if (blk < nblk) {
    shA[tid] = 0; shB[tid] = 0;
    __syncthreads();
    const int base = blk * EPB;
    const int lim = min(EPB, E - base);
    for (int i = tid; i < lim; i += 256) {
      int s = ei[base + i], d = ei[E + base + i];
      esrc[i] = s; edst[i] = d;
      atomicAdd(&shA[d >> 8], 1);
      atomicAdd(&shB[s >> 8], 1);
    }
    __syncthreads();
    if (tid < nbins) {
      hist[tid * nblk + blk] = shA[tid];
      hist[HALF + tid * nblk + blk] = shB[tid];
    }
  }
  grid_bar(cnt, NG, tid);

  // ---- P2: scan1 over hist (blocks < nb1) || WhT transpose (64 blocks) ----
  if (blk < nb1) {
    const int M = 2 * HALF;
    const int i0 = blk * 1024 + tid * 4;
    int v0 = (i0 + 0 < M) ? hist[i0 + 0] : 0;
    int v1 = (i0 + 1 < M) ? hist[i0 + 1] : 0;
    int v2 = (i0 + 2 < M) ? hist[i0 + 2] : 0;
    int v3 = (i0 + 3 < M) ? hist[i0 + 3] : 0;
    int tsum = v0 + v1 + v2 + v3;
    shA[tid] = tsum;
    __syncthreads();
#pragma unroll
    for (int off = 1; off < 256; off <<= 1) {
      int add = (tid >= off) ? shA[tid - off] : 0;
      __syncthreads();
      shA[tid] += add;
      __syncthreads();
    }
    int texcl = shA[tid] - tsum;
    if (tid == 255) partials[blk] = shA[255];
    if (i0 + 0 < M) hist[i0 + 0] = texcl;
    if (i0 + 1 < M) hist[i0 + 1] = texcl + v0;
    if (i0 + 2 < M) hist[i0 + 2] = texcl + v0 + v1;
    if (i0 + 3 < M) hist[i0 + 3] = texcl + v0 + v1 + v2;
  } else if (blk < nb1 + 64) {
    int i = (blk - nb1) * 256 + tid;  // 64 blocks x 256 = 16384 = 128*128
    int k = i >> 7, c = i & 127;
    WhT[c * 128 + k] = (f16)W[i];
  }
  grid_bar(cnt, 2 * NG, tid);

  // ---- P3: scan2 (block 0): exclusive scan of partials[0..nb1) ----
  if (blk == 0) {
    int v = (tid < nb1) ? partials[tid] : 0;
    shA[tid] = v;
    __syncthreads();
#pragma unroll
    for (int off = 1; off < 256; off <<= 1) {
      int add = (tid >= off) ? shA[tid - off] : 0;
      __syncthreads();
      shA[tid] += add;
      __syncthreads();
    }
    if (tid < nb1) partials[tid] = shA[tid] - v;
  }
  grid_bar(cnt, 3 * NG, tid);

  // ---- P4: partition into coarse buckets (edges from LDS) ----
  if (blk < nblk) {
    if (tid < nbins) {
      int ia = tid * nblk + blk;
      int ib = HALF + tid * nblk + blk;
      shA[tid] = hist[ia] + partials[ia >> 10];
      shB[tid] = hist[ib] + partials[ib >> 10] - E;
    }
    __syncthreads();
    const int base = blk * EPB;
    const int lim = min(EPB, E - base);
    for (int i = tid; i < lim; i += 256) {
      int s = esrc[i], d = edst[i];
      int pa = atomicAdd(&shA[d >> 8], 1);
      ebA[pa] = (s << 8) | (d & 255);
      int pb = atomicAdd(&shB[s >> 8], 1);
      ebB[pb] = (unsigned char)(s & 255);
    }
  }
  grid_bar(cnt, 4 * NG, tid);

  // ---- P5: per-bucket fine pass: deg -> dis, then CSR offs + srcs ----
  if (blk < nbins) {
    const int node = blk * 256 + tid;
    // deg
    {
      int i0 = HALF + blk * nblk;
      const int bs = hist[i0] + partials[i0 >> 10] - E;
      int be = E;
      if (blk + 1 < nbins) {
        int i1 = HALF + (blk + 1) * nblk;
        be = hist[i1] + partials[i1 >> 10] - E;
      }
      shA[tid] = 0;
      __syncthreads();
      for (int j = bs + tid; j < be; j += 256) atomicAdd(&shA[ebB[j]], 1);
      __syncthreads();
      if (node < N) dis[node] = rsqrtf(1.0f + (float)shA[tid]);
      __syncthreads();
    }
    // csr
    {
      int i0 = blk * nblk;
      const int bs = hist[i0] + partials[i0 >> 10];
      int be = E;
      if (blk + 1 < nbins) {
        int i1 = (blk + 1) * nblk;
        be = hist[i1] + partials[i1 >> 10];
      }
      shA[tid] = 0;
      __syncthreads();
      for (int j = bs + tid; j < be; j += 256) atomicAdd(&shA[ebA[j] & 255], 1);
      __syncthreads();
      int cnt_ = shA[tid];
      shB[tid] = cnt_;
      __syncthreads();
#pragma unroll
      for (int off = 1; off < 256; off <<= 1) {
        int add = (tid >= off) ? shB[tid - off] : 0;
        __syncthreads();
        shB[tid] += add;
        __syncthreads();
      }
      int gpos = bs + shB[tid] - cnt_;
      if (node < N) offs[node] = gpos;
      shC[tid] = gpos;
      __syncthreads();
      for (int j = bs + tid; j < be; j += 256) {
        int v = ebA[j];
        int p = atomicAdd(&shC[v & 255], 1);
        srcs[p] = v >> 8;
      }
      if (blk == 0 && tid == 0) offs[N] = E;
    }
  }
}

// MFMA GEMM: t2h[r][c] = fp16( dis[r] * sum_k x[r][k] * W[k][c] ).
// 256 thr = 4 waves; wave w owns rows [blk*64 + w*16, +16), all 128 cols.
// Per wave: 8 col-tiles x 4 k-chunks of mfma_f32_16x16x32_f16.
// C/D layout: col = lane&15, row = (lane>>4)*4 + reg  [guide §3, m89].
__global__ __launch_bounds__(256) void k_gemm_mfma(
    const float* __restrict__ x, const f16* __restrict__ WhT,
    const float* __restrict__ dis, __half* __restrict__ t2h, int N) {
  __shared__ __align__(16) f16 cs[4][16][136];  // stride 272B = 17x16B
  const int tid = threadIdx.x;
  const int w = tid >> 6, l = tid & 63;
  const int l15 = l & 15, lg = l >> 4;
  const int wr0 = blockIdx.x * 64 + w * 16;
  const int arow = wr0 + l15;
  const bool avalid = arow < N;

  f32x4 acc[8];
#pragma unroll
  for (int ct = 0; ct < 8; ++ct) acc[ct] = (f32x4){0.f, 0.f, 0.f, 0.f};

#pragma unroll
  for (int kc = 0; kc < 4; ++kc) {
    f16x8 af;
    if (avalid) {
      const float4* ap = (const float4*)(x + (size_t)arow * 128 + kc * 32 + lg * 8);
      float4 a0 = ap[0], a1 = ap[1];
      af[0] = (f16)a0.x; af[1] = (f16)a0.y; af[2] = (f16)a0.z; af[3] = (f16)a0.w;
      af[4] = (f16)a1.x; af[5] = (f16)a1.y; af[6] = (f16)a1.z; af[7] = (f16)a1.w;
    } else {
#pragma unroll
      for (int j = 0; j < 8; ++j) af[j] = (f16)0.f;
    }
#pragma unroll
    for (int ct = 0; ct < 8; ++ct) {
      f16x8 bf = *(const f16x8*)(WhT + (ct * 16 + l15) * 128 + kc * 32 + lg * 8);
      acc[ct] = __builtin_amdgcn_mfma_f32_16x16x32_f16(af, bf, acc[ct], 0, 0, 0);
    }
  }

  // scale rows by dis and stash (transposed per-wave) in LDS
  float d4[4];
#pragma unroll
  for (int j = 0; j < 4; ++j) {
    int r = wr0 + lg * 4 + j;
    d4[j] = (r < N) ? dis[r] : 0.f;
  }
#pragma unroll
  for (int ct = 0; ct < 8; ++ct)
#pragma unroll
    for (int j = 0; j < 4; ++j)
      cs[w][lg * 4 + j][ct * 16 + l15] = (f16)(d4[j] * acc[ct][j]);
  __syncthreads();

  // coalesced write-out: 4 iters x 64 lanes x 16B
#pragma unroll
  for (int it = 0; it < 4; ++it) {
    int t = it * 64 + l;
    int row = t >> 4, seg = t & 15;
    int gr = wr0 + row;
    if (gr < N)
      *(f16x8*)((f16*)t2h + (size_t)gr * 128 + seg * 8) = *(const f16x8*)&cs[w][row][seg * 8];
  }
}

// One 64-lane wave per node; lane owns __half2 at col=lane*2 (r7-proven form).
__global__ __launch_bounds__(256) void k_gather(
    const int* __restrict__ offs, const int* __restrict__ srcs,
    const __half* __restrict__ t2h, const float* __restrict__ dis,
    const float* __restrict__ bias, float* __restrict__ out, int N) {
  const int node = blockIdx.x * 4 + (threadIdx.x >> 6);
  const int lane = threadIdx.x & 63;
  if (node >= N) return;

  const int s = offs[node];
  const int e = offs[node + 1];
  const __half2* t2h2 = (const __half2*)t2h;

  float2 acc = __half22float2(t2h2[(size_t)node * 64 + lane]);  // self loop
  int j = s;
  for (; j + 3 < e; j += 4) {
    int s0 = srcs[j], s1 = srcs[j + 1], s2 = srcs[j + 2], s3 = srcs[j + 3];
    float2 v0 = __half22float2(t2h2[(size_t)s0 * 64 + lane]);
    float2 v1 = __half22float2(t2h2[(size_t)s1 * 64 + lane]);
    float2 v2 = __half22float2(t2h2[(size_t)s2 * 64 + lane]);
    float2 v3 = __half22float2(t2h2[(size_t)s3 * 64 + lane]);
    acc.x += (v0.x + v1.x) + (v2.x + v3.x);
    acc.y += (v0.y + v1.y) + (v2.y + v3.y);
  }
  for (; j < e; ++j) {
    float2 v = __half22float2(t2h2[(size_t)srcs[j] * 64 + lane]);
    acc.x += v.x;
    acc.y += v.y;
  }

  const float dn = dis[node];
  const float2 b = *(const float2*)(bias + (size_t)lane * 2);
  float2 r = make_float2(dn * acc.x + b.x, dn * acc.y + b.y);
  *(float2*)(out + (size_t)node * 128 + (size_t)lane * 2) = r;
}

extern "C" void kernel_launch(void* const* d_in, const int* in_sizes, int n_in,
                              void* d_out, int out_size, void* d_ws, size_t ws_size,
                              hipStream_t stream) {
  const float* x = (const float*)d_in[0];
  const int* ei = (const int*)d_in[1];   // int64 in reference, int32 on device: [2,E] flat
  const float* W = (const float*)d_in[2];
  const float* bias = (const float*)d_in[3];
  float* out = (float*)d_out;

  const int N = in_sizes[0] / 128;
  const int E = in_sizes[1] / 2;
  const int NBLK = cdiv(E, EPB);    // edge blocks (196)
  const int NBINS = cdiv(N, 256);   // coarse node buckets (196)
  const int M = 2 * NBINS * NBLK;   // concatenated hist length
  const int NB1 = cdiv(M, 1024);    // scan stage-1 blocks (76)
  int NG = NBLK > NBINS ? NBLK : NBINS;           // 196 <= 256 CUs -> co-resident
  if (NB1 + 64 > NG) NG = NB1 + 64;

  // Workspace. Overlay region (hist|partials|ebA|ebB ~4.4MB) aliases t2h
  // (12.8MB): dead before k_gemm_mfma writes t2h. Counter is outside overlay.
  __half* t2h = (__half*)d_ws;
  int* hist = (int*)d_ws;                      // [M]
  int* partials = hist + M;                    // [<=256]
  int* ebA = partials + 256;                   // [E]  (src<<8)|(dst&255), dst-bucketed
  unsigned char* ebB = (unsigned char*)(ebA + E);  // [E] src&255, src-bucketed
  float* dis = (float*)(t2h + (size_t)N * 128);    // [N]
  int* offs = (int*)(dis + N);                 // [N+1]
  int* srcs = offs + (N + 1);                  // [E]
  f16* WhT = (f16*)(srcs + E);                 // [128*128] fp16 B^T
  int* cnt = (int*)(WhT + 128 * 128);          // [1] grid-barrier counter

  hipMemsetAsync(cnt, 0, sizeof(int), stream);
  k_build<<<NG, 256, 0, stream>>>(ei, E, N, NBLK, NBINS, NB1, NG,
                                  hist, partials, ebA, ebB, dis, offs, srcs,
                                  W, WhT, cnt);
  k_gemm_mfma<<<cdiv(N, 64), 256, 0, stream>>>(x, WhT, dis, t2h, N);
  k_gather<<<cdiv(N, 4), 256, 0, stream>>>(offs, srcs, t2h, dis, bias, out, N);
}

// Round 10
// 103.923 us; speedup vs baseline: 1.7808x; 1.7808x over previous
//
#include <hip/hip_runtime.h>
#include <hip/hip_fp16.h>

// GCN layer on MI355X — CSR-gather, atomic-free CSR build, fp16 MFMA GEMM.
// out[c] = dis[c] * ( sum_{e: dst=c} t2[src_e] + t2[c] ) + bias
// t2[i] = dis[i] * (x @ W)[i], dis[i] = rsqrt(1 + outdeg(i)).
//
// Round-9 post-mortem: single-kernel build with spin grid-barriers was 121us
// alone (VALUBusy 0.8%, occ 8.7% -> ~95% barrier wait; device-scope polling
// across 8 XCDs costs ~25us/barrier). REVERTED to the r7 multi-kernel chain
// (112us proven). Kept only: WhT transpose folded into k_hist (64 parallel
// blocks, no serial tail), k_deg+k_csr merged (same grid), gather unroll 8.

#define EPB 4096  // edges per k_hist/k_part block

typedef _Float16 f16;
typedef f16 f16x8 __attribute__((ext_vector_type(8)));
typedef float f32x4 __attribute__((ext_vector_type(4)));

static inline int cdiv(int a, int b) { return (a + b - 1) / b; }

// P1: coarse histograms, transposed layout hist[bin*nblk + blk] (dst) and
// hist[HALF + bin*nblk + blk] (src), HALF = nbins*nblk.
// Blocks 0..63 also transpose W -> WhT fp16 (256 elems each, parallel).
__global__ __launch_bounds__(256) void k_hist(const int* __restrict__ ei, int E,
                                              int* __restrict__ hist, int nblk, int nbins,
                                              const float* __restrict__ W,
                                              f16* __restrict__ WhT) {
  __shared__ int ha[256], hb[256];
  const int tid = threadIdx.x, blk = blockIdx.x;
  ha[tid] = 0; hb[tid] = 0;
  __syncthreads();
  const int base = blk * EPB;
  for (int i = tid; i < EPB; i += 256) {
    int e = base + i;
    if (e >= E) break;
    int src = ei[e];
    int dst = ei[E + e];
    atomicAdd(&ha[dst >> 8], 1);
    atomicAdd(&hb[src >> 8], 1);
  }
  if (blk < 64) {  // W[k][c] -> WhT[c][k], 64 blocks x 256 = 16384 elems
    int i = blk * 256 + tid;
    int k = i >> 7, c = i & 127;
    WhT[c * 128 + k] = (f16)W[i];
  }
  __syncthreads();
  if (tid < nbins) {
    hist[tid * nblk + blk] = ha[tid];
    hist[nbins * nblk + tid * nblk + blk] = hb[tid];
  }
}

// Hierarchical exclusive scan stage 1 (in place), 1024 elems/block.
// Consumers add partials[idx>>10]; no stage-3 pass.
__global__ __launch_bounds__(256) void k_scan1(int* __restrict__ a,
                                               int* __restrict__ partials, int M) {
  __shared__ int ws[256];
  const int tid = threadIdx.x;
  const int i0 = blockIdx.x * 1024 + tid * 4;
  int v0 = (i0 + 0 < M) ? a[i0 + 0] : 0;
  int v1 = (i0 + 1 < M) ? a[i0 + 1] : 0;
  int v2 = (i0 + 2 < M) ? a[i0 + 2] : 0;
  int v3 = (i0 + 3 < M) ? a[i0 + 3] : 0;
  int tsum = v0 + v1 + v2 + v3;
  ws[tid] = tsum;
  __syncthreads();
#pragma unroll
  for (int off = 1; off < 256; off <<= 1) {
    int add = (tid >= off) ? ws[tid - off] : 0;
    __syncthreads();
    ws[tid] += add;
    __syncthreads();
  }
  int texcl = ws[tid] - tsum;
  if (tid == 255) partials[blockIdx.x] = ws[255];
  if (i0 + 0 < M) a[i0 + 0] = texcl;
  if (i0 + 1 < M) a[i0 + 1] = texcl + v0;
  if (i0 + 2 < M) a[i0 + 2] = texcl + v0 + v1;
  if (i0 + 3 < M) a[i0 + 3] = texcl + v0 + v1 + v2;
}

// Stage 2: single block, nb <= 256 partials, exclusive in place.
__global__ __launch_bounds__(256) void k_scan2(int* __restrict__ p, int nb) {
  __shared__ int ws[256];
  const int tid = threadIdx.x;
  int v = (tid < nb) ? p[tid] : 0;
  ws[tid] = v;
  __syncthreads();
#pragma unroll
  for (int off = 1; off < 256; off <<= 1) {
    int add = (tid >= off) ? ws[tid - off] : 0;
    __syncthreads();
    ws[tid] += add;
    __syncthreads();
  }
  if (tid < nb) p[tid] = ws[tid] - v;
}

// P2: partition edges into coarse buckets. ebA[posA] = (src<<8)|(dst&255)
// (dst-bucketed), ebB[posB] = src&255 (src-bucketed, uchar). Plain stores only.
__global__ __launch_bounds__(256) void k_part(const int* __restrict__ ei, int E,
                                              const int* __restrict__ hist,
                                              const int* __restrict__ partials,
                                              int nblk, int nbins,
                                              int* __restrict__ ebA,
                                              unsigned char* __restrict__ ebB) {
  __shared__ int cA[256], cB[256];
  const int tid = threadIdx.x, blk = blockIdx.x;
  const int HALF = nbins * nblk;
  if (tid < nbins) {
    int ia = tid * nblk + blk;
    int ib = HALF + tid * nblk + blk;
    cA[tid] = hist[ia] + partials[ia >> 10];
    cB[tid] = hist[ib] + partials[ib >> 10] - E;
  }
  __syncthreads();
  const int base = blk * EPB;
  for (int i = tid; i < EPB; i += 256) {
    int e = base + i;
    if (e >= E) break;
    int src = ei[e];
    int dst = ei[E + e];
    int pa = atomicAdd(&cA[dst >> 8], 1);
    ebA[pa] = (src << 8) | (dst & 255);
    int pb = atomicAdd(&cB[src >> 8], 1);
    ebB[pb] = (unsigned char)(src & 255);
  }
}

// P3 merged: per coarse bucket b,
//  phase 1 (deg): fine count of src over ebB bucket -> dis = rsqrt(1+cnt)
//  phase 2 (csr): fine count+scan of dst over ebA bucket -> offs, place srcs
__global__ __launch_bounds__(256) void k_bucket(
    const int* __restrict__ ebA, const unsigned char* __restrict__ ebB,
    const int* __restrict__ hist, const int* __restrict__ partials,
    int nblk, int nbins, int E,
    float* __restrict__ dis, int* __restrict__ offs,
    int* __restrict__ srcs, int N) {
  __shared__ int h[256], tmp[256], cur[256];
  const int tid = threadIdx.x, b = blockIdx.x;
  const int HALF = nbins * nblk;
  const int node = b * 256 + tid;

  // --- phase 1: out-degree -> dis ---
  {
    int i0 = HALF + b * nblk;
    const int bs = hist[i0] + partials[i0 >> 10] - E;
    int be = E;
    if (b + 1 < nbins) {
      int i1 = HALF + (b + 1) * nblk;
      be = hist[i1] + partials[i1 >> 10] - E;
    }
    h[tid] = 0;
    __syncthreads();
    for (int j = bs + tid; j < be; j += 256) atomicAdd(&h[ebB[j]], 1);
    __syncthreads();
    if (node < N) dis[node] = rsqrtf(1.0f + (float)h[tid]);
    __syncthreads();
  }

  // --- phase 2: CSR offs + srcs ---
  {
    int i0 = b * nblk;
    const int bs = hist[i0] + partials[i0 >> 10];
    int be = E;
    if (b + 1 < nbins) {
      int i1 = (b + 1) * nblk;
      be = hist[i1] + partials[i1 >> 10];
    }
    h[tid] = 0;
    __syncthreads();
    for (int j = bs + tid; j < be; j += 256) atomicAdd(&h[ebA[j] & 255], 1);
    __syncthreads();
    int cnt = h[tid];
    tmp[tid] = cnt;
    __syncthreads();
#pragma unroll
    for (int off = 1; off < 256; off <<= 1) {
      int add = (tid >= off) ? tmp[tid - off] : 0;
      __syncthreads();
      tmp[tid] += add;
      __syncthreads();
    }
    int gpos = bs + tmp[tid] - cnt;
    if (node < N) offs[node] = gpos;
    cur[tid] = gpos;
    __syncthreads();
    for (int j = bs + tid; j < be; j += 256) {
      int v = ebA[j];
      int p = atomicAdd(&cur[v & 255], 1);
      srcs[p] = v >> 8;
    }
    if (b == 0 && tid == 0) offs[N] = E;
  }
}

// MFMA GEMM: t2h[r][c] = fp16( dis[r] * sum_k x[r][k] * W[k][c] ).
// 256 thr = 4 waves; wave w owns rows [blk*64 + w*16, +16), all 128 cols.
// Per wave: 8 col-tiles x 4 k-chunks of mfma_f32_16x16x32_f16.
// C/D layout: col = lane&15, row = (lane>>4)*4 + reg  [guide §3, m89].
__global__ __launch_bounds__(256) void k_gemm_mfma(
    const float* __restrict__ x, const f16* __restrict__ WhT,
    const float* __restrict__ dis, __half* __restrict__ t2h, int N) {
  __shared__ __align__(16) f16 cs[4][16][136];  // stride 272B = 17x16B
  const int tid = threadIdx.x;
  const int w = tid >> 6, l = tid & 63;
  const int l15 = l & 15, lg = l >> 4;
  const int wr0 = blockIdx.x * 64 + w * 16;
  const int arow = wr0 + l15;
  const bool avalid = arow < N;

  f32x4 acc[8];
#pragma unroll
  for (int ct = 0; ct < 8; ++ct) acc[ct] = (f32x4){0.f, 0.f, 0.f, 0.f};

#pragma unroll
  for (int kc = 0; kc < 4; ++kc) {
    f16x8 af;
    if (avalid) {
      const float4* ap = (const float4*)(x + (size_t)arow * 128 + kc * 32 + lg * 8);
      float4 a0 = ap[0], a1 = ap[1];
      af[0] = (f16)a0.x; af[1] = (f16)a0.y; af[2] = (f16)a0.z; af[3] = (f16)a0.w;
      af[4] = (f16)a1.x; af[5] = (f16)a1.y; af[6] = (f16)a1.z; af[7] = (f16)a1.w;
    } else {
#pragma unroll
      for (int j = 0; j < 8; ++j) af[j] = (f16)0.f;
    }
#pragma unroll
    for (int ct = 0; ct < 8; ++ct) {
      f16x8 bf = *(const f16x8*)(WhT + (ct * 16 + l15) * 128 + kc * 32 + lg * 8);
      acc[ct] = __builtin_amdgcn_mfma_f32_16x16x32_f16(af, bf, acc[ct], 0, 0, 0);
    }
  }

  // scale rows by dis and stash (transposed per-wave) in LDS
  float d4[4];
#pragma unroll
  for (int j = 0; j < 4; ++j) {
    int r = wr0 + lg * 4 + j;
    d4[j] = (r < N) ? dis[r] : 0.f;
  }
#pragma unroll
  for (int ct = 0; ct < 8; ++ct)
#pragma unroll
    for (int j = 0; j < 4; ++j)
      cs[w][lg * 4 + j][ct * 16 + l15] = (f16)(d4[j] * acc[ct][j]);
  __syncthreads();

  // coalesced write-out: 4 iters x 64 lanes x 16B
#pragma unroll
  for (int it = 0; it < 4; ++it) {
    int t = it * 64 + l;
    int row = t >> 4, seg = t & 15;
    int gr = wr0 + row;
    if (gr < N)
      *(f16x8*)((f16*)t2h + (size_t)gr * 128 + seg * 8) = *(const f16x8*)&cs[w][row][seg * 8];
  }
}

// One 64-lane wave per node; lane owns __half2 at col=lane*2 (r7 form,
// unroll deepened 4 -> 8 for more rows in flight; mean degree ~16).
__global__ __launch_bounds__(256) void k_gather(
    const int* __restrict__ offs, const int* __restrict__ srcs,
    const __half* __restrict__ t2h, const float* __restrict__ dis,
    const float* __restrict__ bias, float* __restrict__ out, int N) {
  const int node = blockIdx.x * 4 + (threadIdx.x >> 6);
  const int lane = threadIdx.x & 63;
  if (node >= N) return;

  const int s = offs[node];
  const int e = offs[node + 1];
  const __half2* t2h2 = (const __half2*)t2h;

  float2 acc = __half22float2(t2h2[(size_t)node * 64 + lane]);  // self loop
  float2 acc2 = make_float2(0.f, 0.f);
  int j = s;
  for (; j + 7 < e; j += 8) {
    int s0 = srcs[j], s1 = srcs[j + 1], s2 = srcs[j + 2], s3 = srcs[j + 3];
    int s4 = srcs[j + 4], s5 = srcs[j + 5], s6 = srcs[j + 6], s7 = srcs[j + 7];
    float2 v0 = __half22float2(t2h2[(size_t)s0 * 64 + lane]);
    float2 v1 = __half22float2(t2h2[(size_t)s1 * 64 + lane]);
    float2 v2 = __half22float2(t2h2[(size_t)s2 * 64 + lane]);
    float2 v3 = __half22float2(t2h2[(size_t)s3 * 64 + lane]);
    float2 v4 = __half22float2(t2h2[(size_t)s4 * 64 + lane]);
    float2 v5 = __half22float2(t2h2[(size_t)s5 * 64 + lane]);
    float2 v6 = __half22float2(t2h2[(size_t)s6 * 64 + lane]);
    float2 v7 = __half22float2(t2h2[(size_t)s7 * 64 + lane]);
    acc.x += (v0.x + v1.x) + (v2.x + v3.x);
    acc.y += (v0.y + v1.y) + (v2.y + v3.y);
    acc2.x += (v4.x + v5.x) + (v6.x + v7.x);
    acc2.y += (v4.y + v5.y) + (v6.y + v7.y);
  }
  for (; j + 3 < e; j += 4) {
    int s0 = srcs[j], s1 = srcs[j + 1], s2 = srcs[j + 2], s3 = srcs[j + 3];
    float2 v0 = __half22float2(t2h2[(size_t)s0 * 64 + lane]);
    float2 v1 = __half22float2(t2h2[(size_t)s1 * 64 + lane]);
    float2 v2 = __half22float2(t2h2[(size_t)s2 * 64 + lane]);
    float2 v3 = __half22float2(t2h2[(size_t)s3 * 64 + lane]);
    acc.x += (v0.x + v1.x) + (v2.x + v3.x);
    acc.y += (v0.y + v1.y) + (v2.y + v3.y);
  }
  for (; j < e; ++j) {
    float2 v = __half22float2(t2h2[(size_t)srcs[j] * 64 + lane]);
    acc.x += v.x;
    acc.y += v.y;
  }
  acc.x += acc2.x;
  acc.y += acc2.y;

  const float dn = dis[node];
  const float2 b = *(const float2*)(bias + (size_t)lane * 2);
  float2 r = make_float2(dn * acc.x + b.x, dn * acc.y + b.y);
  *(float2*)(out + (size_t)node * 128 + (size_t)lane * 2) = r;
}

extern "C" void kernel_launch(void* const* d_in, const int* in_sizes, int n_in,
                              void* d_out, int out_size, void* d_ws, size_t ws_size,
                              hipStream_t stream) {
  const float* x = (const float*)d_in[0];
  const int* ei = (const int*)d_in[1];   // int64 in reference, int32 on device: [2,E] flat
  const float* W = (const float*)d_in[2];
  const float* bias = (const float*)d_in[3];
  float* out = (float*)d_out;

  const int N = in_sizes[0] / 128;
  const int E = in_sizes[1] / 2;
  const int NBLK = cdiv(E, EPB);    // edge blocks (196)
  const int NBINS = cdiv(N, 256);   // coarse node buckets (196)
  const int M = 2 * NBINS * NBLK;   // concatenated hist length
  const int NB1 = cdiv(M, 1024);    // scan stage-1 blocks (<=256 required)

  // Workspace. Overlay region (hist|partials|ebA|ebB ~4.4MB) aliases t2h
  // (12.8MB): dead before k_gemm_mfma writes t2h. WhT outside overlay.
  __half* t2h = (__half*)d_ws;
  int* hist = (int*)d_ws;                      // [M]
  int* partials = hist + M;                    // [<=256]
  int* ebA = partials + 256;                   // [E]  (src<<8)|(dst&255), dst-bucketed
  unsigned char* ebB = (unsigned char*)(ebA + E);  // [E] src&255, src-bucketed
  float* dis = (float*)(t2h + (size_t)N * 128);    // [N]
  int* offs = (int*)(dis + N);                 // [N+1]
  int* srcs = offs + (N + 1);                  // [E]
  f16* WhT = (f16*)(srcs + E);                 // [128*128] fp16 B^T

  k_hist<<<NBLK, 256, 0, stream>>>(ei, E, hist, NBLK, NBINS, W, WhT);
  k_scan1<<<NB1, 256, 0, stream>>>(hist, partials, M);
  k_scan2<<<1, 256, 0, stream>>>(partials, NB1);
  k_part<<<NBLK, 256, 0, stream>>>(ei, E, hist, partials, NBLK, NBINS, ebA, ebB);
  k_bucket<<<NBINS, 256, 0, stream>>>(ebA, ebB, hist, partials, NBLK, NBINS, E,
                                      dis, offs, srcs, N);
  k_gemm_mfma<<<cdiv(N, 64), 256, 0, stream>>>(x, WhT, dis, t2h, N);
  k_gather<<<cdiv(N, 4), 256, 0, stream>>>(offs, srcs, t2h, dis, bias, out, N);
}

// Round 11
// 100.242 us; speedup vs baseline: 1.8462x; 1.0367x over previous
//
#include <hip/hip_runtime.h>
#include <hip/hip_fp16.h>

// GCN layer on MI355X — CSR-gather, atomic-free CSR build, fp16 MFMA GEMM.
// out[c] = dis[c] * ( sum_{e: dst=c} t2[src_e] + t2[c] ) + bias
// t2[i] = dis[i] * (x @ W)[i], dis[i] = rsqrt(1 + outdeg(i)).
//
// Round-10 (103.9us) post-mortem: r9's grid-barrier fusion refuted (spin
// barriers ~25us each); multi-kernel chain + parallel WhT fold + merged
// bucket kernel all confirmed. This round: (1) k_scan2 deleted — consumers
// scan the 76 partials in LDS themselves; (2) int4-vectorized edge reads in
// k_hist/k_part; (3) srcs pre-scaled by 64 (gather addr math).

#define EPB 4096  // edges per k_hist/k_part block

typedef _Float16 f16;
typedef f16 f16x8 __attribute__((ext_vector_type(8)));
typedef float f32x4 __attribute__((ext_vector_type(4)));

static inline int cdiv(int a, int b) { return (a + b - 1) / b; }

// P1: coarse histograms, transposed layout hist[bin*nblk + blk] (dst) and
// hist[HALF + bin*nblk + blk] (src), HALF = nbins*nblk.
// Blocks 0..63 also transpose W -> WhT fp16 (256 elems each, parallel).
__global__ __launch_bounds__(256) void k_hist(const int* __restrict__ ei, int E,
                                              int* __restrict__ hist, int nblk, int nbins,
                                              const float* __restrict__ W,
                                              f16* __restrict__ WhT) {
  __shared__ int ha[256], hb[256];
  const int tid = threadIdx.x, blk = blockIdx.x;
  ha[tid] = 0; hb[tid] = 0;
  __syncthreads();
  const int base = blk * EPB;
  const int lim = min(EPB, E - base);
  if ((E & 3) == 0) {
    for (int i = tid * 4; i + 3 < lim; i += 1024) {
      int4 s4 = *(const int4*)(ei + base + i);
      int4 d4 = *(const int4*)(ei + E + base + i);
      atomicAdd(&ha[d4.x >> 8], 1); atomicAdd(&hb[s4.x >> 8], 1);
      atomicAdd(&ha[d4.y >> 8], 1); atomicAdd(&hb[s4.y >> 8], 1);
      atomicAdd(&ha[d4.z >> 8], 1); atomicAdd(&hb[s4.z >> 8], 1);
      atomicAdd(&ha[d4.w >> 8], 1); atomicAdd(&hb[s4.w >> 8], 1);
    }
    for (int i = (lim & ~3) + tid; i < lim; i += 256) {
      atomicAdd(&ha[ei[E + base + i] >> 8], 1);
      atomicAdd(&hb[ei[base + i] >> 8], 1);
    }
  } else {
    for (int i = tid; i < lim; i += 256) {
      atomicAdd(&ha[ei[E + base + i] >> 8], 1);
      atomicAdd(&hb[ei[base + i] >> 8], 1);
    }
  }
  if (blk < 64) {  // W[k][c] -> WhT[c][k], 64 blocks x 256 = 16384 elems
    int i = blk * 256 + tid;
    int k = i >> 7, c = i & 127;
    WhT[c * 128 + k] = (f16)W[i];
  }
  __syncthreads();
  if (tid < nbins) {
    hist[tid * nblk + blk] = ha[tid];
    hist[nbins * nblk + tid * nblk + blk] = hb[tid];
  }
}

// Hierarchical exclusive scan stage 1 (in place), 1024 elems/block.
// partials keeps RAW block sums; consumers scan them in LDS themselves.
__global__ __launch_bounds__(256) void k_scan1(int* __restrict__ a,
                                               int* __restrict__ partials, int M) {
  __shared__ int ws[256];
  const int tid = threadIdx.x;
  const int i0 = blockIdx.x * 1024 + tid * 4;
  int v0 = (i0 + 0 < M) ? a[i0 + 0] : 0;
  int v1 = (i0 + 1 < M) ? a[i0 + 1] : 0;
  int v2 = (i0 + 2 < M) ? a[i0 + 2] : 0;
  int v3 = (i0 + 3 < M) ? a[i0 + 3] : 0;
  int tsum = v0 + v1 + v2 + v3;
  ws[tid] = tsum;
  __syncthreads();
#pragma unroll
  for (int off = 1; off < 256; off <<= 1) {
    int add = (tid >= off) ? ws[tid - off] : 0;
    __syncthreads();
    ws[tid] += add;
    __syncthreads();
  }
  int texcl = ws[tid] - tsum;
  if (tid == 255) partials[blockIdx.x] = ws[255];
  if (i0 + 0 < M) a[i0 + 0] = texcl;
  if (i0 + 1 < M) a[i0 + 1] = texcl + v0;
  if (i0 + 2 < M) a[i0 + 2] = texcl + v0 + v1;
  if (i0 + 3 < M) a[i0 + 3] = texcl + v0 + v1 + v2;
}

// Shared helper: exclusive-scan nb1 (<=256) raw partials into shP.
__device__ __forceinline__ void scan_partials(const int* __restrict__ partials,
                                              int nb1, int* shP, int tid) {
  int v = (tid < nb1) ? partials[tid] : 0;
  shP[tid] = v;
  __syncthreads();
#pragma unroll
  for (int off = 1; off < 256; off <<= 1) {
    int add = (tid >= off) ? shP[tid - off] : 0;
    __syncthreads();
    shP[tid] += add;
    __syncthreads();
  }
  int excl = shP[tid] - v;
  __syncthreads();
  shP[tid] = excl;
  __syncthreads();
}

// P2: partition edges into coarse buckets. ebA[posA] = (src<<8)|(dst&255)
// (dst-bucketed), ebB[posB] = src&255 (src-bucketed, uchar). Plain stores only.
__global__ __launch_bounds__(256) void k_part(const int* __restrict__ ei, int E,
                                              const int* __restrict__ hist,
                                              const int* __restrict__ partials, int nb1,
                                              int nblk, int nbins,
                                              int* __restrict__ ebA,
                                              unsigned char* __restrict__ ebB) {
  __shared__ int cA[256], cB[256], shP[256];
  const int tid = threadIdx.x, blk = blockIdx.x;
  const int HALF = nbins * nblk;
  scan_partials(partials, nb1, shP, tid);
  if (tid < nbins) {
    int ia = tid * nblk + blk;
    int ib = HALF + tid * nblk + blk;
    cA[tid] = hist[ia] + shP[ia >> 10];
    cB[tid] = hist[ib] + shP[ib >> 10] - E;
  }
  __syncthreads();
  const int base = blk * EPB;
  const int lim = min(EPB, E - base);
  if ((E & 3) == 0) {
    for (int i = tid * 4; i + 3 < lim; i += 1024) {
      int4 s4 = *(const int4*)(ei + base + i);
      int4 d4 = *(const int4*)(ei + E + base + i);
      int pa, pb;
      pa = atomicAdd(&cA[d4.x >> 8], 1); ebA[pa] = (s4.x << 8) | (d4.x & 255);
      pb = atomicAdd(&cB[s4.x >> 8], 1); ebB[pb] = (unsigned char)(s4.x & 255);
      pa = atomicAdd(&cA[d4.y >> 8], 1); ebA[pa] = (s4.y << 8) | (d4.y & 255);
      pb = atomicAdd(&cB[s4.y >> 8], 1); ebB[pb] = (unsigned char)(s4.y & 255);
      pa = atomicAdd(&cA[d4.z >> 8], 1); ebA[pa] = (s4.z << 8) | (d4.z & 255);
      pb = atomicAdd(&cB[s4.z >> 8], 1); ebB[pb] = (unsigned char)(s4.z & 255);
      pa = atomicAdd(&cA[d4.w >> 8], 1); ebA[pa] = (s4.w << 8) | (d4.w & 255);
      pb = atomicAdd(&cB[s4.w >> 8], 1); ebB[pb] = (unsigned char)(s4.w & 255);
    }
    for (int i = (lim & ~3) + tid; i < lim; i += 256) {
      int s = ei[base + i], d = ei[E + base + i];
      int pa = atomicAdd(&cA[d >> 8], 1); ebA[pa] = (s << 8) | (d & 255);
      int pb = atomicAdd(&cB[s >> 8], 1); ebB[pb] = (unsigned char)(s & 255);
    }
  } else {
    for (int i = tid; i < lim; i += 256) {
      int s = ei[base + i], d = ei[E + base + i];
      int pa = atomicAdd(&cA[d >> 8], 1); ebA[pa] = (s << 8) | (d & 255);
      int pb = atomicAdd(&cB[s >> 8], 1); ebB[pb] = (unsigned char)(s & 255);
    }
  }
}

// P3 merged: per coarse bucket b,
//  phase 1 (deg): fine count of src over ebB bucket -> dis = rsqrt(1+cnt)
//  phase 2 (csr): fine count+scan of dst over ebA bucket -> offs, place srcs
// srcs stored PRE-SCALED by 64 (half2-row units) for the gather.
__global__ __launch_bounds__(256) void k_bucket(
    const int* __restrict__ ebA, const unsigned char* __restrict__ ebB,
    const int* __restrict__ hist, const int* __restrict__ partials, int nb1,
    int nblk, int nbins, int E,
    float* __restrict__ dis, int* __restrict__ offs,
    int* __restrict__ srcs, int N) {
  __shared__ int h[256], tmp[256], cur[256], shP[256];
  const int tid = threadIdx.x, b = blockIdx.x;
  const int HALF = nbins * nblk;
  const int node = b * 256 + tid;
  scan_partials(partials, nb1, shP, tid);

  // --- phase 1: out-degree -> dis ---
  {
    int i0 = HALF + b * nblk;
    const int bs = hist[i0] + shP[i0 >> 10] - E;
    int be = E;
    if (b + 1 < nbins) {
      int i1 = HALF + (b + 1) * nblk;
      be = hist[i1] + shP[i1 >> 10] - E;
    }
    h[tid] = 0;
    __syncthreads();
    for (int j = bs + tid; j < be; j += 256) atomicAdd(&h[ebB[j]], 1);
    __syncthreads();
    if (node < N) dis[node] = rsqrtf(1.0f + (float)h[tid]);
    __syncthreads();
  }

  // --- phase 2: CSR offs + srcs ---
  {
    int i0 = b * nblk;
    const int bs = hist[i0] + shP[i0 >> 10];
    int be = E;
    if (b + 1 < nbins) {
      int i1 = (b + 1) * nblk;
      be = hist[i1] + shP[i1 >> 10];
    }
    h[tid] = 0;
    __syncthreads();
    for (int j = bs + tid; j < be; j += 256) atomicAdd(&h[ebA[j] & 255], 1);
    __syncthreads();
    int cnt = h[tid];
    tmp[tid] = cnt;
    __syncthreads();
#pragma unroll
    for (int off = 1; off < 256; off <<= 1) {
      int add = (tid >= off) ? tmp[tid - off] : 0;
      __syncthreads();
      tmp[tid] += add;
      __syncthreads();
    }
    int gpos = bs + tmp[tid] - cnt;
    if (node < N) offs[node] = gpos;
    cur[tid] = gpos;
    __syncthreads();
    for (int j = bs + tid; j < be; j += 256) {
      int v = ebA[j];
      int p = atomicAdd(&cur[v & 255], 1);
      srcs[p] = (v >> 8) << 6;  // pre-scaled: src * 64 half2-units
    }
    if (b == 0 && tid == 0) offs[N] = E;
  }
}

// MFMA GEMM: t2h[r][c] = fp16( dis[r] * sum_k x[r][k] * W[k][c] ).
// 256 thr = 4 waves; wave w owns rows [blk*64 + w*16, +16), all 128 cols.
// Per wave: 8 col-tiles x 4 k-chunks of mfma_f32_16x16x32_f16.
// C/D layout: col = lane&15, row = (lane>>4)*4 + reg  [guide §3, m89].
__global__ __launch_bounds__(256) void k_gemm_mfma(
    const float* __restrict__ x, const f16* __restrict__ WhT,
    const float* __restrict__ dis, __half* __restrict__ t2h, int N) {
  __shared__ __align__(16) f16 cs[4][16][136];  // stride 272B = 17x16B
  const int tid = threadIdx.x;
  const int w = tid >> 6, l = tid & 63;
  const int l15 = l & 15, lg = l >> 4;
  const int wr0 = blockIdx.x * 64 + w * 16;
  const int arow = wr0 + l15;
  const bool avalid = arow < N;

  f32x4 acc[8];
#pragma unroll
  for (int ct = 0; ct < 8; ++ct) acc[ct] = (f32x4){0.f, 0.f, 0.f, 0.f};

#pragma unroll
  for (int kc = 0; kc < 4; ++kc) {
    f16x8 af;
    if (avalid) {
      const float4* ap = (const float4*)(x + (size_t)arow * 128 + kc * 32 + lg * 8);
      float4 a0 = ap[0], a1 = ap[1];
      af[0] = (f16)a0.x; af[1] = (f16)a0.y; af[2] = (f16)a0.z; af[3] = (f16)a0.w;
      af[4] = (f16)a1.x; af[5] = (f16)a1.y; af[6] = (f16)a1.z; af[7] = (f16)a1.w;
    } else {
#pragma unroll
      for (int j = 0; j < 8; ++j) af[j] = (f16)0.f;
    }
#pragma unroll
    for (int ct = 0; ct < 8; ++ct) {
      f16x8 bf = *(const f16x8*)(WhT + (ct * 16 + l15) * 128 + kc * 32 + lg * 8);
      acc[ct] = __builtin_amdgcn_mfma_f32_16x16x32_f16(af, bf, acc[ct], 0, 0, 0);
    }
  }

  // scale rows by dis and stash (transposed per-wave) in LDS
  float d4[4];
#pragma unroll
  for (int j = 0; j < 4; ++j) {
    int r = wr0 + lg * 4 + j;
    d4[j] = (r < N) ? dis[r] : 0.f;
  }
#pragma unroll
  for (int ct = 0; ct < 8; ++ct)
#pragma unroll
    for (int j = 0; j < 4; ++j)
      cs[w][lg * 4 + j][ct * 16 + l15] = (f16)(d4[j] * acc[ct][j]);
  __syncthreads();

  // coalesced write-out: 4 iters x 64 lanes x 16B
#pragma unroll
  for (int it = 0; it < 4; ++it) {
    int t = it * 64 + l;
    int row = t >> 4, seg = t & 15;
    int gr = wr0 + row;
    if (gr < N)
      *(f16x8*)((f16*)t2h + (size_t)gr * 128 + seg * 8) = *(const f16x8*)&cs[w][row][seg * 8];
  }
}

// One 64-lane wave per node; lane owns __half2 at col=lane*2.
// srcs entries are pre-scaled (src*64) half2-row offsets.
__global__ __launch_bounds__(256) void k_gather(
    const int* __restrict__ offs, const int* __restrict__ srcs,
    const __half* __restrict__ t2h, const float* __restrict__ dis,
    const float* __restrict__ bias, float* __restrict__ out, int N) {
  const int node = blockIdx.x * 4 + (threadIdx.x >> 6);
  const int lane = threadIdx.x & 63;
  if (node >= N) return;

  const int s = offs[node];
  const int e = offs[node + 1];
  const __half2* t2h2 = (const __half2*)t2h;

  float2 acc = __half22float2(t2h2[(size_t)node * 64 + lane]);  // self loop
  float2 acc2 = make_float2(0.f, 0.f);
  int j = s;
  for (; j + 7 < e; j += 8) {
    int s0 = srcs[j], s1 = srcs[j + 1], s2 = srcs[j + 2], s3 = srcs[j + 3];
    int s4 = srcs[j + 4], s5 = srcs[j + 5], s6 = srcs[j + 6], s7 = srcs[j + 7];
    float2 v0 = __half22float2(t2h2[(size_t)s0 + lane]);
    float2 v1 = __half22float2(t2h2[(size_t)s1 + lane]);
    float2 v2 = __half22float2(t2h2[(size_t)s2 + lane]);
    float2 v3 = __half22float2(t2h2[(size_t)s3 + lane]);
    float2 v4 = __half22float2(t2h2[(size_t)s4 + lane]);
    float2 v5 = __half22float2(t2h2[(size_t)s5 + lane]);
    float2 v6 = __half22float2(t2h2[(size_t)s6 + lane]);
    float2 v7 = __half22float2(t2h2[(size_t)s7 + lane]);
    acc.x += (v0.x + v1.x) + (v2.x + v3.x);
    acc.y += (v0.y + v1.y) + (v2.y + v3.y);
    acc2.x += (v4.x + v5.x) + (v6.x + v7.x);
    acc2.y += (v4.y + v5.y) + (v6.y + v7.y);
  }
  for (; j + 3 < e; j += 4) {
    int s0 = srcs[j], s1 = srcs[j + 1], s2 = srcs[j + 2], s3 = srcs[j + 3];
    float2 v0 = __half22float2(t2h2[(size_t)s0 + lane]);
    float2 v1 = __half22float2(t2h2[(size_t)s1 + lane]);
    float2 v2 = __half22float2(t2h2[(size_t)s2 + lane]);
    float2 v3 = __half22float2(t2h2[(size_t)s3 + lane]);
    acc.x += (v0.x + v1.x) + (v2.x + v3.x);
    acc.y += (v0.y + v1.y) + (v2.y + v3.y);
  }
  for (; j < e; ++j) {
    float2 v = __half22float2(t2h2[(size_t)srcs[j] + lane]);
    acc.x += v.x;
    acc.y += v.y;
  }
  acc.x += acc2.x;
  acc.y += acc2.y;

  const float dn = dis[node];
  const float2 b = *(const float2*)(bias + (size_t)lane * 2);
  float2 r = make_float2(dn * acc.x + b.x, dn * acc.y + b.y);
  *(float2*)(out + (size_t)node * 128 + (size_t)lane * 2) = r;
}

extern "C" void kernel_launch(void* const* d_in, const int* in_sizes, int n_in,
                              void* d_out, int out_size, void* d_ws, size_t ws_size,
                              hipStream_t stream) {
  const float* x = (const float*)d_in[0];
  const int* ei = (const int*)d_in[1];   // int64 in reference, int32 on device: [2,E] flat
  const float* W = (const float*)d_in[2];
  const float* bias = (const float*)d_in[3];
  float* out = (float*)d_out;

  const int N = in_sizes[0] / 128;
  const int E = in_sizes[1] / 2;
  const int NBLK = cdiv(E, EPB);    // edge blocks (196)
  const int NBINS = cdiv(N, 256);   // coarse node buckets (196)
  const int M = 2 * NBINS * NBLK;   // concatenated hist length
  const int NB1 = cdiv(M, 1024);    // scan stage-1 blocks (<=256 required)

  // Workspace. Overlay region (hist|partials|ebA|ebB ~4.4MB) aliases t2h
  // (12.8MB): dead before k_gemm_mfma writes t2h. WhT outside overlay.
  __half* t2h = (__half*)d_ws;
  int* hist = (int*)d_ws;                      // [M]
  int* partials = hist + M;                    // [<=256] raw block sums
  int* ebA = partials + 256;                   // [E]  (src<<8)|(dst&255), dst-bucketed
  unsigned char* ebB = (unsigned char*)(ebA + E);  // [E] src&255, src-bucketed
  float* dis = (float*)(t2h + (size_t)N * 128);    // [N]
  int* offs = (int*)(dis + N);                 // [N+1]
  int* srcs = offs + (N + 1);                  // [E] pre-scaled src*64
  f16* WhT = (f16*)(srcs + E);                 // [128*128] fp16 B^T

  k_hist<<<NBLK, 256, 0, stream>>>(ei, E, hist, NBLK, NBINS, W, WhT);
  k_scan1<<<NB1, 256, 0, stream>>>(hist, partials, M);
  k_part<<<NBLK, 256, 0, stream>>>(ei, E, hist, partials, NB1, NBLK, NBINS, ebA, ebB);
  k_bucket<<<NBINS, 256, 0, stream>>>(ebA, ebB, hist, partials, NB1, NBLK, NBINS, E,
                                      dis, offs, srcs, N);
  k_gemm_mfma<<<cdiv(N, 64), 256, 0, stream>>>(x, WhT, dis, t2h, N);
  k_gather<<<cdiv(N, 4), 256, 0, stream>>>(offs, srcs, t2h, dis, bias, out, N);
}